// Round 2
// baseline (256.342 us; speedup 1.0000x reference)
//
#include <hip/hip_runtime.h>
#include <hip/hip_bf16.h>
#include <cfloat>

// Problem constants (from reference)
#define BB   16
#define LL   4096
#define CC   9
#define DIN  512
#define DOUT 128
#define VV   96

// Tiling
#define MT 64   // rows per block
#define KT 32   // k-tile
#define APAD 4
#define WPAD 4
#define QPAD 4

__global__ __launch_bounds__(256)
void fused_attn_kernel(const float* __restrict__ X,      // [B*L, DIN]
                       const float* __restrict__ W,      // [DOUT, DIN]
                       const float* __restrict__ PE,     // [VV, DOUT]
                       const int*   __restrict__ CIDX,   // [B*L, CC]
                       const int*   __restrict__ CMASK,  // [B*L, CC] bool-as-int32
                       const int*   __restrict__ SLEN,   // [B]
                       float*       __restrict__ OUT)    // [B*L, DOUT]
{
    __shared__ float As[KT][MT + APAD];     // [k][m]
    __shared__ float Ws[KT][DOUT + WPAD];   // [k][n]
    __shared__ float qs[MT][DOUT + QPAD];   // [m][n]

    const int t    = threadIdx.x;
    const int row0 = blockIdx.x * MT;

    const int tm = t >> 5;   // 0..7
    const int tn = t & 31;   // 0..31

    float acc[8][4];
    #pragma unroll
    for (int i = 0; i < 8; ++i)
        #pragma unroll
        for (int j = 0; j < 4; ++j) acc[i][j] = 0.f;

    for (int k0 = 0; k0 < DIN; k0 += KT) {
        __syncthreads();
        // ---- stage A tile: 64 m x 32 k  (512 float4 chunks) ----
        #pragma unroll
        for (int it = 0; it < 2; ++it) {
            int c  = t + it * 256;
            int m  = c >> 3;
            int kq = c & 7;
            float4 va = *(const float4*)(X + (size_t)(row0 + m) * DIN + k0 + kq * 4);
            As[kq * 4 + 0][m] = va.x;
            As[kq * 4 + 1][m] = va.y;
            As[kq * 4 + 2][m] = va.z;
            As[kq * 4 + 3][m] = va.w;
        }
        // ---- stage W tile: 128 n x 32 k (1024 float4 chunks) ----
        #pragma unroll
        for (int it = 0; it < 4; ++it) {
            int c  = t + it * 256;
            int n  = c >> 3;
            int kq = c & 7;
            float4 vw = *(const float4*)(W + (size_t)n * DIN + k0 + kq * 4);
            Ws[kq * 4 + 0][n] = vw.x;
            Ws[kq * 4 + 1][n] = vw.y;
            Ws[kq * 4 + 2][n] = vw.z;
            Ws[kq * 4 + 3][n] = vw.w;
        }
        __syncthreads();
        // ---- compute ----
        #pragma unroll 8
        for (int k = 0; k < KT; ++k) {
            float4 b4 = *(const float4*)&Ws[k][tn * 4];
            float4 a0 = *(const float4*)&As[k][tm * 8];
            float4 a1 = *(const float4*)&As[k][tm * 8 + 4];
            float a[8] = {a0.x, a0.y, a0.z, a0.w, a1.x, a1.y, a1.z, a1.w};
            float b[4] = {b4.x, b4.y, b4.z, b4.w};
            #pragma unroll
            for (int i = 0; i < 8; ++i)
                #pragma unroll
                for (int j = 0; j < 4; ++j)
                    acc[i][j] = fmaf(a[i], b[j], acc[i][j]);
        }
    }

    // ---- q tile to LDS ----
    #pragma unroll
    for (int i = 0; i < 8; ++i) {
        float4 v = make_float4(acc[i][0], acc[i][1], acc[i][2], acc[i][3]);
        *(float4*)&qs[tm * 8 + i][tn * 4] = v;
    }
    __syncthreads();

    // ---- attention epilogue: 4 lanes per row ----
    const int r   = t >> 2;    // 0..63
    const int sub = t & 3;     // dim block of 32
    const size_t gr = (size_t)row0 + r;
    const int bb = (int)(gr >> 12);      // /LL
    const int l  = (int)(gr & (LL - 1));
    const bool inlen = l < SLEN[bb];

    int  ci[CC];
    bool vm[CC];
    bool any = false;
    #pragma unroll
    for (int c = 0; c < CC; ++c) {
        ci[c] = CIDX[gr * CC + c];
        vm[c] = CMASK[gr * CC + c] != 0;
        any = any || vm[c];
    }

    float qv[32];
    #pragma unroll
    for (int j4 = 0; j4 < 8; ++j4) {
        float4 v = *(const float4*)&qs[r][sub * 32 + j4 * 4];
        qv[j4 * 4 + 0] = v.x;
        qv[j4 * 4 + 1] = v.y;
        qv[j4 * 4 + 2] = v.z;
        qv[j4 * 4 + 3] = v.w;
    }

    float sc[CC];
    #pragma unroll
    for (int c = 0; c < CC; ++c) {
        const float* pe = PE + (size_t)ci[c] * DOUT + sub * 32;
        float s = 0.f;
        #pragma unroll
        for (int j4 = 0; j4 < 8; ++j4) {
            float4 v = *(const float4*)(pe + j4 * 4);
            s = fmaf(qv[j4 * 4 + 0], v.x, s);
            s = fmaf(qv[j4 * 4 + 1], v.y, s);
            s = fmaf(qv[j4 * 4 + 2], v.z, s);
            s = fmaf(qv[j4 * 4 + 3], v.w, s);
        }
        s += __shfl_xor(s, 1);
        s += __shfl_xor(s, 2);
        sc[c] = s;
    }

    float mx = -FLT_MAX;
    #pragma unroll
    for (int c = 0; c < CC; ++c)
        if (vm[c]) mx = fmaxf(mx, sc[c]);

    float e[CC];
    float den = 0.f;
    #pragma unroll
    for (int c = 0; c < CC; ++c) {
        e[c] = vm[c] ? __expf(sc[c] - mx) : 0.f;
        den += e[c];
    }
    const float scale = (any && inlen) ? (1.f / den) : 0.f;

    float o[32];
    #pragma unroll
    for (int j = 0; j < 32; ++j) o[j] = 0.f;
    #pragma unroll
    for (int c = 0; c < CC; ++c) {
        const float w = e[c];
        const float* pe = PE + (size_t)ci[c] * DOUT + sub * 32;
        #pragma unroll
        for (int j4 = 0; j4 < 8; ++j4) {
            float4 v = *(const float4*)(pe + j4 * 4);
            o[j4 * 4 + 0] = fmaf(w, v.x, o[j4 * 4 + 0]);
            o[j4 * 4 + 1] = fmaf(w, v.y, o[j4 * 4 + 1]);
            o[j4 * 4 + 2] = fmaf(w, v.z, o[j4 * 4 + 2]);
            o[j4 * 4 + 3] = fmaf(w, v.w, o[j4 * 4 + 3]);
        }
    }

    float* op = OUT + gr * DOUT + sub * 32;
    #pragma unroll
    for (int j4 = 0; j4 < 8; ++j4) {
        float4 v = make_float4(o[j4 * 4 + 0] * scale, o[j4 * 4 + 1] * scale,
                               o[j4 * 4 + 2] * scale, o[j4 * 4 + 3] * scale);
        *(float4*)(op + j4 * 4) = v;
    }
}

extern "C" void kernel_launch(void* const* d_in, const int* in_sizes, int n_in,
                              void* d_out, int out_size, void* d_ws, size_t ws_size,
                              hipStream_t stream) {
    const float* X  = (const float*)d_in[0];
    const float* W  = (const float*)d_in[1];
    const float* PE = (const float*)d_in[2];
    const int*   CI = (const int*)d_in[3];
    const int*   CM = (const int*)d_in[4];
    const int*   SL = (const int*)d_in[5];
    float* OUT = (float*)d_out;

    const int rows = BB * LL;            // 65536
    dim3 grid(rows / MT);                // 1024
    dim3 block(256);
    hipLaunchKernelGGL(fused_attn_kernel, grid, block, 0, stream,
                       X, W, PE, CI, CM, SL, OUT);
}

// Round 3
// 196.412 us; speedup vs baseline: 1.3051x; 1.3051x over previous
//
#include <hip/hip_runtime.h>
#include <hip/hip_bf16.h>
#include <cfloat>

// Problem constants
#define BB   16
#define LL   4096
#define CC   9
#define DIN  512
#define DOUT 128
#define VV   96

// Tiling
#define MT    64      // rows per block
#define KT    32      // k-tile
#define ALD   40      // A LDS row stride in bf16 elems (32 + 8 pad) = 80 B
#define BLD   40      // B LDS row stride
#define QLD   132     // q LDS row stride in f32 elems

typedef __attribute__((ext_vector_type(8))) short bf16x8;
typedef __attribute__((ext_vector_type(4))) float f32x4;

__device__ __forceinline__ unsigned short bf_rne(float x) {
    unsigned int u = __float_as_uint(x);
    u += 0x7fffu + ((u >> 16) & 1u);
    return (unsigned short)(u >> 16);
}
__device__ __forceinline__ float bf_f(unsigned short s) {
    return __uint_as_float(((unsigned int)s) << 16);
}

__global__ __launch_bounds__(256)
void fused_attn_kernel(const float* __restrict__ X,      // [B*L, DIN]
                       const float* __restrict__ W,      // [DOUT, DIN]
                       const float* __restrict__ PE,     // [VV, DOUT]
                       const int*   __restrict__ CIDX,   // [B*L, CC]
                       const int*   __restrict__ CMASK,  // [B*L, CC] int32 bool
                       const int*   __restrict__ SLEN,   // [B]
                       float*       __restrict__ OUT)    // [B*L, DOUT]
{
    __shared__ union {
        struct {
            unsigned short Ah[MT][ALD];
            unsigned short Al[MT][ALD];
            unsigned short Bh[DOUT][BLD];
            unsigned short Bl[DOUT][BLD];
        } s;
        float qs[MT][QLD];
    } u;

    const int t    = threadIdx.x;
    const int row0 = blockIdx.x * MT;
    const int lane = t & 63;
    const int wid  = t >> 6;            // 0..3
    const int wr   = (wid >> 1) * 32;   // wave row offset: 0 / 32
    const int wc   = (wid & 1) * 64;    // wave col offset: 0 / 64

    f32x4 acc[2][4];
    #pragma unroll
    for (int mf = 0; mf < 2; ++mf)
        #pragma unroll
        for (int nf = 0; nf < 4; ++nf) acc[mf][nf] = (f32x4)0.f;

    const int fr = lane & 15;
    const int kb = (lane >> 4) * 8;

    for (int k0 = 0; k0 < DIN; k0 += KT) {
        __syncthreads();
        // ---- stage A tile 64x32 fp32 -> hi/lo bf16 ----
        #pragma unroll
        for (int it = 0; it < 2; ++it) {
            int c = t + it * 256;
            int m = c >> 3, kq = c & 7;
            float4 v = *(const float4*)(X + (size_t)(row0 + m) * DIN + k0 + kq * 4);
            unsigned short h0 = bf_rne(v.x), h1 = bf_rne(v.y),
                           h2 = bf_rne(v.z), h3 = bf_rne(v.w);
            unsigned short l0 = bf_rne(v.x - bf_f(h0)), l1 = bf_rne(v.y - bf_f(h1)),
                           l2 = bf_rne(v.z - bf_f(h2)), l3 = bf_rne(v.w - bf_f(h3));
            uint2 hw, lw;
            hw.x = (unsigned int)h0 | ((unsigned int)h1 << 16);
            hw.y = (unsigned int)h2 | ((unsigned int)h3 << 16);
            lw.x = (unsigned int)l0 | ((unsigned int)l1 << 16);
            lw.y = (unsigned int)l2 | ((unsigned int)l3 << 16);
            *(uint2*)&u.s.Ah[m][kq * 4] = hw;
            *(uint2*)&u.s.Al[m][kq * 4] = lw;
        }
        // ---- stage B (W) tile 128x32 fp32 -> hi/lo bf16 ----
        #pragma unroll
        for (int it = 0; it < 4; ++it) {
            int c = t + it * 256;
            int n = c >> 3, kq = c & 7;
            float4 v = *(const float4*)(W + (size_t)n * DIN + k0 + kq * 4);
            unsigned short h0 = bf_rne(v.x), h1 = bf_rne(v.y),
                           h2 = bf_rne(v.z), h3 = bf_rne(v.w);
            unsigned short l0 = bf_rne(v.x - bf_f(h0)), l1 = bf_rne(v.y - bf_f(h1)),
                           l2 = bf_rne(v.z - bf_f(h2)), l3 = bf_rne(v.w - bf_f(h3));
            uint2 hw, lw;
            hw.x = (unsigned int)h0 | ((unsigned int)h1 << 16);
            hw.y = (unsigned int)h2 | ((unsigned int)h3 << 16);
            lw.x = (unsigned int)l0 | ((unsigned int)l1 << 16);
            lw.y = (unsigned int)l2 | ((unsigned int)l3 << 16);
            *(uint2*)&u.s.Bh[n][kq * 4] = hw;
            *(uint2*)&u.s.Bl[n][kq * 4] = lw;
        }
        __syncthreads();
        // ---- MFMA: hi*hi + hi*lo + lo*hi ----
        bf16x8 ah[2], al[2], bh[4], bl[4];
        #pragma unroll
        for (int mf = 0; mf < 2; ++mf) {
            ah[mf] = *(const bf16x8*)&u.s.Ah[wr + mf * 16 + fr][kb];
            al[mf] = *(const bf16x8*)&u.s.Al[wr + mf * 16 + fr][kb];
        }
        #pragma unroll
        for (int nf = 0; nf < 4; ++nf) {
            bh[nf] = *(const bf16x8*)&u.s.Bh[wc + nf * 16 + fr][kb];
            bl[nf] = *(const bf16x8*)&u.s.Bl[wc + nf * 16 + fr][kb];
        }
        #pragma unroll
        for (int mf = 0; mf < 2; ++mf)
            #pragma unroll
            for (int nf = 0; nf < 4; ++nf) {
                acc[mf][nf] = __builtin_amdgcn_mfma_f32_16x16x32_bf16(ah[mf], bh[nf], acc[mf][nf], 0, 0, 0);
                acc[mf][nf] = __builtin_amdgcn_mfma_f32_16x16x32_bf16(ah[mf], bl[nf], acc[mf][nf], 0, 0, 0);
                acc[mf][nf] = __builtin_amdgcn_mfma_f32_16x16x32_bf16(al[mf], bh[nf], acc[mf][nf], 0, 0, 0);
            }
    }

    // ---- write q tile to LDS (D layout: col=lane&15, row=(lane>>4)*4+j) ----
    __syncthreads();
    #pragma unroll
    for (int mf = 0; mf < 2; ++mf)
        #pragma unroll
        for (int nf = 0; nf < 4; ++nf) {
            int cn    = wc + nf * 16 + fr;
            int rbase = wr + mf * 16 + (lane >> 4) * 4;
            #pragma unroll
            for (int j = 0; j < 4; ++j)
                u.qs[rbase + j][cn] = acc[mf][nf][j];
        }
    __syncthreads();

    // ---- attention epilogue: 4 lanes per row (verified round-2 code) ----
    const int r   = t >> 2;
    const int sub = t & 3;
    const size_t gr = (size_t)row0 + r;
    const int bb = (int)(gr >> 12);
    const int l  = (int)(gr & (LL - 1));
    const bool inlen = l < SLEN[bb];

    int  ci[CC];
    bool vm[CC];
    bool any = false;
    #pragma unroll
    for (int c = 0; c < CC; ++c) {
        ci[c] = CIDX[gr * CC + c];
        vm[c] = CMASK[gr * CC + c] != 0;
        any = any || vm[c];
    }

    float qv[32];
    #pragma unroll
    for (int j4 = 0; j4 < 8; ++j4) {
        float4 v = *(const float4*)&u.qs[r][sub * 32 + j4 * 4];
        qv[j4 * 4 + 0] = v.x;
        qv[j4 * 4 + 1] = v.y;
        qv[j4 * 4 + 2] = v.z;
        qv[j4 * 4 + 3] = v.w;
    }

    float sc[CC];
    #pragma unroll
    for (int c = 0; c < CC; ++c) {
        const float* pe = PE + (size_t)ci[c] * DOUT + sub * 32;
        float s = 0.f;
        #pragma unroll
        for (int j4 = 0; j4 < 8; ++j4) {
            float4 v = *(const float4*)(pe + j4 * 4);
            s = fmaf(qv[j4 * 4 + 0], v.x, s);
            s = fmaf(qv[j4 * 4 + 1], v.y, s);
            s = fmaf(qv[j4 * 4 + 2], v.z, s);
            s = fmaf(qv[j4 * 4 + 3], v.w, s);
        }
        s += __shfl_xor(s, 1);
        s += __shfl_xor(s, 2);
        sc[c] = s;
    }

    float mx = -FLT_MAX;
    #pragma unroll
    for (int c = 0; c < CC; ++c)
        if (vm[c]) mx = fmaxf(mx, sc[c]);

    float e[CC];
    float den = 0.f;
    #pragma unroll
    for (int c = 0; c < CC; ++c) {
        e[c] = vm[c] ? __expf(sc[c] - mx) : 0.f;
        den += e[c];
    }
    const float scale = (any && inlen) ? (1.f / den) : 0.f;

    float o[32];
    #pragma unroll
    for (int j = 0; j < 32; ++j) o[j] = 0.f;
    #pragma unroll
    for (int c = 0; c < CC; ++c) {
        const float w = e[c];
        const float* pe = PE + (size_t)ci[c] * DOUT + sub * 32;
        #pragma unroll
        for (int j4 = 0; j4 < 8; ++j4) {
            float4 v = *(const float4*)(pe + j4 * 4);
            o[j4 * 4 + 0] = fmaf(w, v.x, o[j4 * 4 + 0]);
            o[j4 * 4 + 1] = fmaf(w, v.y, o[j4 * 4 + 1]);
            o[j4 * 4 + 2] = fmaf(w, v.z, o[j4 * 4 + 2]);
            o[j4 * 4 + 3] = fmaf(w, v.w, o[j4 * 4 + 3]);
        }
    }

    float* op = OUT + gr * DOUT + sub * 32;
    #pragma unroll
    for (int j4 = 0; j4 < 8; ++j4) {
        float4 v = make_float4(o[j4 * 4 + 0] * scale, o[j4 * 4 + 1] * scale,
                               o[j4 * 4 + 2] * scale, o[j4 * 4 + 3] * scale);
        *(float4*)(op + j4 * 4) = v;
    }
}

extern "C" void kernel_launch(void* const* d_in, const int* in_sizes, int n_in,
                              void* d_out, int out_size, void* d_ws, size_t ws_size,
                              hipStream_t stream) {
    const float* X  = (const float*)d_in[0];
    const float* W  = (const float*)d_in[1];
    const float* PE = (const float*)d_in[2];
    const int*   CI = (const int*)d_in[3];
    const int*   CM = (const int*)d_in[4];
    const int*   SL = (const int*)d_in[5];
    float* OUT = (float*)d_out;

    const int rows = BB * LL;            // 65536
    dim3 grid(rows / MT);                // 1024
    dim3 block(256);
    hipLaunchKernelGGL(fused_attn_kernel, grid, block, 0, stream,
                       X, W, PE, CI, CM, SL, OUT);
}

// Round 4
// 59.355 us; speedup vs baseline: 4.3188x; 3.3091x over previous
//
#include <hip/hip_runtime.h>
#include <hip/hip_bf16.h>
#include <hip/hip_fp16.h>
#include <cfloat>

// Problem constants
#define BB   16
#define LL   4096
#define CC   9
#define DIN  512
#define DOUT 128
#define VV   96

// ---------------------------------------------------------------------------
// Kernel 1: PW[v][k] = sum_o PE[v][o] * W[o][k]   (fp32 accumulate -> fp16)
// PW is [VV][DIN] fp16 in workspace. 96 blocks x 256 threads, 2 outputs/thread.
// ---------------------------------------------------------------------------
__global__ __launch_bounds__(256)
void pw_kernel(const float* __restrict__ W,    // [DOUT][DIN]
               const float* __restrict__ PE,   // [VV][DOUT]
               __half*      __restrict__ PW)   // [VV][DIN]
{
    const int v = blockIdx.x;          // 0..95
    const int k = threadIdx.x * 2;     // 0..510
    const float* per = PE + v * DOUT;
    float a0 = 0.f, a1 = 0.f;
    #pragma unroll 8
    for (int o = 0; o < DOUT; ++o) {
        float p = per[o];
        float2 w2 = *(const float2*)(W + (size_t)o * DIN + k);
        a0 = fmaf(p, w2.x, a0);
        a1 = fmaf(p, w2.y, a1);
    }
    __half2 h = __floats2half2_rn(a0, a1);
    *(__half2*)(PW + (size_t)v * DIN + k) = h;
}

// ---------------------------------------------------------------------------
// Kernel 2: streaming scores + softmax + weighted PE sum.
// 16 lanes per row, 4 rows per wave, 16 rows per block, grid = 4096.
// ---------------------------------------------------------------------------
__global__ __launch_bounds__(256)
void attn_kernel(const float*  __restrict__ X,     // [B*L][DIN]
                 const __half* __restrict__ PW,    // [VV][DIN]
                 const float*  __restrict__ PE,    // [VV][DOUT]
                 const int*    __restrict__ CIDX,  // [B*L][CC]
                 const int*    __restrict__ CMASK, // [B*L][CC]
                 const int*    __restrict__ SLEN,  // [B]
                 float*        __restrict__ OUT)   // [B*L][DOUT]
{
    const int t    = threadIdx.x;
    const int lane = t & 63;
    const int il   = lane & 15;    // lane within row-group
    const int rsub = lane >> 4;    // row within wave
    const int wid  = t >> 6;       // wave within block
    const int row  = blockIdx.x * 16 + wid * 4 + rsub;   // 0..65535

    const int  b     = row >> 12;
    const int  l     = row & (LL - 1);
    const bool inlen = l < SLEN[b];

    // ---- x chunk: elems [il*8 + 128*j .. +8), j = 0..3  (32 f32) ----
    const float* xr = X + (size_t)row * DIN;
    float xv[32];
    #pragma unroll
    for (int j = 0; j < 4; ++j) {
        float4 v0 = *(const float4*)(xr + il * 8 + 128 * j);
        float4 v1 = *(const float4*)(xr + il * 8 + 128 * j + 4);
        xv[j * 8 + 0] = v0.x; xv[j * 8 + 1] = v0.y;
        xv[j * 8 + 2] = v0.z; xv[j * 8 + 3] = v0.w;
        xv[j * 8 + 4] = v1.x; xv[j * 8 + 5] = v1.y;
        xv[j * 8 + 6] = v1.z; xv[j * 8 + 7] = v1.w;
    }

    // ---- candidate indices + mask ----
    int  ci[CC];
    bool vm[CC];
    bool any = false;
    #pragma unroll
    for (int c = 0; c < CC; ++c) {
        ci[c] = CIDX[(size_t)row * CC + c];
        vm[c] = CMASK[(size_t)row * CC + c] != 0;
        any = any || vm[c];
    }

    // ---- scores: sc[c] = x . PW[ci[c]]  (fp16 PW, fp32 accumulate) ----
    float sc[CC];
    #pragma unroll
    for (int c = 0; c < CC; ++c) {
        const __half* pw = PW + (size_t)ci[c] * DIN;
        float s = 0.f;
        #pragma unroll
        for (int j = 0; j < 4; ++j) {
            uint4 u = *(const uint4*)(pw + il * 8 + 128 * j);
            __half2 h0, h1, h2, h3;
            *(unsigned int*)&h0 = u.x;
            *(unsigned int*)&h1 = u.y;
            *(unsigned int*)&h2 = u.z;
            *(unsigned int*)&h3 = u.w;
            float2 f0 = __half22float2(h0);
            float2 f1 = __half22float2(h1);
            float2 f2 = __half22float2(h2);
            float2 f3 = __half22float2(h3);
            s = fmaf(xv[j * 8 + 0], f0.x, s);
            s = fmaf(xv[j * 8 + 1], f0.y, s);
            s = fmaf(xv[j * 8 + 2], f1.x, s);
            s = fmaf(xv[j * 8 + 3], f1.y, s);
            s = fmaf(xv[j * 8 + 4], f2.x, s);
            s = fmaf(xv[j * 8 + 5], f2.y, s);
            s = fmaf(xv[j * 8 + 6], f3.x, s);
            s = fmaf(xv[j * 8 + 7], f3.y, s);
        }
        // reduce across the 16 lanes of this row-group
        s += __shfl_xor(s, 1);
        s += __shfl_xor(s, 2);
        s += __shfl_xor(s, 4);
        s += __shfl_xor(s, 8);
        sc[c] = s;
    }

    // ---- masked softmax (redundant per lane) ----
    float mx = -FLT_MAX;
    #pragma unroll
    for (int c = 0; c < CC; ++c)
        if (vm[c]) mx = fmaxf(mx, sc[c]);

    float e[CC];
    float den = 0.f;
    #pragma unroll
    for (int c = 0; c < CC; ++c) {
        e[c] = vm[c] ? __expf(sc[c] - mx) : 0.f;
        den += e[c];
    }
    const float scale = (any && inlen) ? (1.f / den) : 0.f;

    // ---- out dims [il*8 .. +8) = sum_c e[c] * PE[ci[c]] ----
    float o[8];
    #pragma unroll
    for (int j = 0; j < 8; ++j) o[j] = 0.f;
    #pragma unroll
    for (int c = 0; c < CC; ++c) {
        const float w = e[c];
        const float* pe = PE + (size_t)ci[c] * DOUT + il * 8;
        float4 p0 = *(const float4*)pe;
        float4 p1 = *(const float4*)(pe + 4);
        o[0] = fmaf(w, p0.x, o[0]); o[1] = fmaf(w, p0.y, o[1]);
        o[2] = fmaf(w, p0.z, o[2]); o[3] = fmaf(w, p0.w, o[3]);
        o[4] = fmaf(w, p1.x, o[4]); o[5] = fmaf(w, p1.y, o[5]);
        o[6] = fmaf(w, p1.z, o[6]); o[7] = fmaf(w, p1.w, o[7]);
    }

    float* op = OUT + (size_t)row * DOUT + il * 8;
    *(float4*)op       = make_float4(o[0] * scale, o[1] * scale, o[2] * scale, o[3] * scale);
    *(float4*)(op + 4) = make_float4(o[4] * scale, o[5] * scale, o[6] * scale, o[7] * scale);
}

extern "C" void kernel_launch(void* const* d_in, const int* in_sizes, int n_in,
                              void* d_out, int out_size, void* d_ws, size_t ws_size,
                              hipStream_t stream) {
    const float* X  = (const float*)d_in[0];
    const float* W  = (const float*)d_in[1];
    const float* PE = (const float*)d_in[2];
    const int*   CI = (const int*)d_in[3];
    const int*   CM = (const int*)d_in[4];
    const int*   SL = (const int*)d_in[5];
    float* OUT = (float*)d_out;
    __half* PW = (__half*)d_ws;          // 96*512*2 B = 96 KiB

    hipLaunchKernelGGL(pw_kernel, dim3(VV), dim3(256), 0, stream, W, PE, PW);

    const int rows = BB * LL;            // 65536
    hipLaunchKernelGGL(attn_kernel, dim3(rows / 16), dim3(256), 0, stream,
                       X, PW, PE, CI, CM, SL, OUT);
}

// Round 6
// 57.384 us; speedup vs baseline: 4.4671x; 1.0343x over previous
//
#include <hip/hip_runtime.h>
#include <hip/hip_bf16.h>
#include <hip/hip_fp16.h>
#include <cfloat>

// Problem constants
#define BB   16
#define LL   4096
#define CC   9
#define DIN  512
#define DOUT 128
#define VV   96

typedef _Float16 h2 __attribute__((ext_vector_type(2)));

#if defined(__has_builtin)
#if __has_builtin(__builtin_amdgcn_fdot2)
#define FDOT2(a, b, c) __builtin_amdgcn_fdot2((a), (b), (c), false)
#endif
#endif
#ifndef FDOT2
__device__ __forceinline__ float FDOT2(h2 a, h2 b, float c) {
    return c + (float)a[0] * (float)b[0] + (float)a[1] * (float)b[1];
}
#endif

__device__ __forceinline__ h2 pack_h2(float lo, float hi) {
    return __builtin_bit_cast(h2, __builtin_amdgcn_cvt_pkrtz(lo, hi));
}

// ---------------------------------------------------------------------------
// Kernel 1: PW[v][k] = sum_o PE[v][o] * W[o][k]   (fp32 accumulate -> fp16)
// grid (96, 4) x 128 threads: one output per thread, coalesced W reads.
// ---------------------------------------------------------------------------
__global__ __launch_bounds__(128)
void pw_kernel(const float* __restrict__ W,    // [DOUT][DIN]
               const float* __restrict__ PE,   // [VV][DOUT]
               __half*      __restrict__ PW)   // [VV][DIN]
{
    const int v = blockIdx.x;                       // 0..95
    const int k = blockIdx.y * 128 + threadIdx.x;   // 0..511
    const float* per = PE + v * DOUT;
    float a = 0.f;
    #pragma unroll 8
    for (int o = 0; o < DOUT; ++o)
        a = fmaf(per[o], W[(size_t)o * DIN + k], a);
    PW[(size_t)v * DIN + k] = __float2half_rn(a);
}

// ---------------------------------------------------------------------------
// Kernel 2: streaming scores + softmax + weighted PE sum.
// 16 lanes per row, 4 rows per wave, 16 rows per block, grid = 4096.
// ---------------------------------------------------------------------------
__global__ __launch_bounds__(256, 3)
void attn_kernel(const float*  __restrict__ X,     // [B*L][DIN]
                 const __half* __restrict__ PW,    // [VV][DIN]
                 const float*  __restrict__ PE,    // [VV][DOUT]
                 const int*    __restrict__ CIDX,  // [B*L][CC]
                 const int*    __restrict__ CMASK, // [B*L][CC]
                 const int*    __restrict__ SLEN,  // [B]
                 float*        __restrict__ OUT)   // [B*L][DOUT]
{
    const int t    = threadIdx.x;
    const int lane = t & 63;
    const int il   = lane & 15;    // lane within row-group
    const int rsub = lane >> 4;    // row within wave
    const int wid  = t >> 6;       // wave within block
    const int row  = blockIdx.x * 16 + wid * 4 + rsub;   // 0..65535

    const int  b     = row >> 12;
    const int  l     = row & (LL - 1);
    const bool inlen = l < SLEN[b];

    // ---- candidate indices + mask (issue first: PE/PW gathers depend) ----
    int  ci[CC];
    bool vm[CC];
    bool any = false;
    #pragma unroll
    for (int c = 0; c < CC; ++c) {
        ci[c] = CIDX[(size_t)row * CC + c];
        vm[c] = CMASK[(size_t)row * CC + c] != 0;
        any = any || vm[c];
    }

    // ---- x chunk: 32 f32 -> 16 half2 (v_cvt_pkrtz) ----
    const float* xr = X + (size_t)row * DIN;
    float4 xf[8];
    #pragma unroll
    for (int j = 0; j < 4; ++j) {
        xf[j * 2 + 0] = *(const float4*)(xr + il * 8 + 128 * j);
        xf[j * 2 + 1] = *(const float4*)(xr + il * 8 + 128 * j + 4);
    }
    h2 xh[16];
    #pragma unroll
    for (int q = 0; q < 8; ++q) {
        xh[q * 2 + 0] = pack_h2(xf[q].x, xf[q].y);
        xh[q * 2 + 1] = pack_h2(xf[q].z, xf[q].w);
    }

    // ---- scores: sc[c] = x . PW[ci[c]]  (half2 dot2, f32 accumulate) ----
    float sc[CC];
    #pragma unroll
    for (int c = 0; c < CC; ++c) sc[c] = 0.f;

    #pragma unroll
    for (int j = 0; j < 4; ++j) {
        uint4 pwb[CC];
        #pragma unroll
        for (int c = 0; c < CC; ++c)
            pwb[c] = *(const uint4*)(PW + (size_t)ci[c] * DIN + il * 8 + 128 * j);
        #pragma unroll
        for (int c = 0; c < CC; ++c) {
            h2 p0 = __builtin_bit_cast(h2, pwb[c].x);
            h2 p1 = __builtin_bit_cast(h2, pwb[c].y);
            h2 p2 = __builtin_bit_cast(h2, pwb[c].z);
            h2 p3 = __builtin_bit_cast(h2, pwb[c].w);
            float s = sc[c];
            s = FDOT2(xh[j * 4 + 0], p0, s);
            s = FDOT2(xh[j * 4 + 1], p1, s);
            s = FDOT2(xh[j * 4 + 2], p2, s);
            s = FDOT2(xh[j * 4 + 3], p3, s);
            sc[c] = s;
        }
    }
    #pragma unroll
    for (int c = 0; c < CC; ++c) {
        float s = sc[c];
        s += __shfl_xor(s, 1);
        s += __shfl_xor(s, 2);
        s += __shfl_xor(s, 4);
        s += __shfl_xor(s, 8);
        sc[c] = s;
    }

    // ---- masked softmax (redundant per lane) ----
    float mx = -FLT_MAX;
    #pragma unroll
    for (int c = 0; c < CC; ++c)
        if (vm[c]) mx = fmaxf(mx, sc[c]);

    float e[CC];
    float den = 0.f;
    #pragma unroll
    for (int c = 0; c < CC; ++c) {
        e[c] = vm[c] ? __expf(sc[c] - mx) : 0.f;
        den += e[c];
    }
    const float scale = (any && inlen) ? (1.f / den) : 0.f;

    // ---- out dims [il*8 .. +8) = sum_c e[c] * PE[ci[c]] ----
    float o[8];
    #pragma unroll
    for (int j = 0; j < 8; ++j) o[j] = 0.f;
    #pragma unroll
    for (int c = 0; c < CC; ++c) {
        const float w = e[c];
        const float* pe = PE + (size_t)ci[c] * DOUT + il * 8;
        float4 p0 = *(const float4*)pe;
        float4 p1 = *(const float4*)(pe + 4);
        o[0] = fmaf(w, p0.x, o[0]); o[1] = fmaf(w, p0.y, o[1]);
        o[2] = fmaf(w, p0.z, o[2]); o[3] = fmaf(w, p0.w, o[3]);
        o[4] = fmaf(w, p1.x, o[4]); o[5] = fmaf(w, p1.y, o[5]);
        o[6] = fmaf(w, p1.z, o[6]); o[7] = fmaf(w, p1.w, o[7]);
    }

    float* op = OUT + (size_t)row * DOUT + il * 8;
    *(float4*)op       = make_float4(o[0] * scale, o[1] * scale, o[2] * scale, o[3] * scale);
    *(float4*)(op + 4) = make_float4(o[4] * scale, o[5] * scale, o[6] * scale, o[7] * scale);
}

extern "C" void kernel_launch(void* const* d_in, const int* in_sizes, int n_in,
                              void* d_out, int out_size, void* d_ws, size_t ws_size,
                              hipStream_t stream) {
    const float* X  = (const float*)d_in[0];
    const float* W  = (const float*)d_in[1];
    const float* PE = (const float*)d_in[2];
    const int*   CI = (const int*)d_in[3];
    const int*   CM = (const int*)d_in[4];
    const int*   SL = (const int*)d_in[5];
    float* OUT = (float*)d_out;
    __half* PW = (__half*)d_ws;          // 96*512*2 B = 96 KiB

    hipLaunchKernelGGL(pw_kernel, dim3(VV, 4), dim3(128), 0, stream, W, PE, PW);

    const int rows = BB * LL;            // 65536
    hipLaunchKernelGGL(attn_kernel, dim3(rows / 16), dim3(256), 0, stream,
                       X, PW, PE, CI, CM, SL, OUT);
}

// Round 7
// 52.180 us; speedup vs baseline: 4.9127x; 1.0997x over previous
//
#include <hip/hip_runtime.h>
#include <hip/hip_bf16.h>
#include <hip/hip_fp16.h>
#include <cfloat>

// Problem constants
#define BB   16
#define LL   4096
#define CC   9
#define DIN  512
#define DOUT 128
#define VV   96

typedef _Float16 h2 __attribute__((ext_vector_type(2)));

#if defined(__has_builtin)
#if __has_builtin(__builtin_amdgcn_fdot2)
#define FDOT2(a, b, c) __builtin_amdgcn_fdot2((a), (b), (c), false)
#endif
#endif
#ifndef FDOT2
__device__ __forceinline__ float FDOT2(h2 a, h2 b, float c) {
    return c + (float)a[0] * (float)b[0] + (float)a[1] * (float)b[1];
}
#endif

__device__ __forceinline__ h2 pack_h2(float lo, float hi) {
    return __builtin_bit_cast(h2, __builtin_amdgcn_cvt_pkrtz(lo, hi));
}

// ---------------------------------------------------------------------------
// Kernel 1: PW[v][k] = sum_o PE[v][o] * W[o][k]   (fp32 accumulate -> fp16)
// ---------------------------------------------------------------------------
__global__ __launch_bounds__(128)
void pw_kernel(const float* __restrict__ W,    // [DOUT][DIN]
               const float* __restrict__ PE,   // [VV][DOUT]
               __half*      __restrict__ PW)   // [VV][DIN]
{
    const int v = blockIdx.x;                       // 0..95
    const int k = blockIdx.y * 128 + threadIdx.x;   // 0..511
    const float* per = PE + v * DOUT;
    float a = 0.f;
    #pragma unroll 8
    for (int o = 0; o < DOUT; ++o)
        a = fmaf(per[o], W[(size_t)o * DIN + k], a);
    PW[(size_t)v * DIN + k] = __float2half_rn(a);
}

// ---------------------------------------------------------------------------
// Kernel 1b: PEh = fp16(PE)   (96*128 elems, half2 per thread)
// ---------------------------------------------------------------------------
__global__ __launch_bounds__(256)
void peh_kernel(const float* __restrict__ PE, __half* __restrict__ PEh)
{
    const int i = blockIdx.x * 256 + threadIdx.x;   // 0..6143 (half2 units)
    float2 f = ((const float2*)PE)[i];
    ((__half2*)PEh)[i] = __floats2half2_rn(f.x, f.y);
}

// ---------------------------------------------------------------------------
// Kernel 2: streaming scores + softmax + weighted PE sum.
// 16 lanes per row, 4 rows per wave, 16 rows per block, grid = 4096.
// Explicit 2-deep software pipeline on the PW gathers.
// ---------------------------------------------------------------------------
template<int J>
__device__ __forceinline__ void pw_issue(uint4 (&buf)[CC],
                                         const __half* const (&pwr)[CC]) {
    #pragma unroll
    for (int c = 0; c < CC; ++c)
        buf[c] = *(const uint4*)(pwr[c] + 128 * J);
}

template<int J>
__device__ __forceinline__ void pw_consume(const uint4 (&buf)[CC],
                                           const h2 (&xh)[16],
                                           float (&sc)[CC]) {
    #pragma unroll
    for (int c = 0; c < CC; ++c) {
        h2 p0 = __builtin_bit_cast(h2, buf[c].x);
        h2 p1 = __builtin_bit_cast(h2, buf[c].y);
        h2 p2 = __builtin_bit_cast(h2, buf[c].z);
        h2 p3 = __builtin_bit_cast(h2, buf[c].w);
        float s = sc[c];
        s = FDOT2(xh[J * 4 + 0], p0, s);
        s = FDOT2(xh[J * 4 + 1], p1, s);
        s = FDOT2(xh[J * 4 + 2], p2, s);
        s = FDOT2(xh[J * 4 + 3], p3, s);
        sc[c] = s;
    }
}

__global__ __launch_bounds__(256, 2)
void attn_kernel(const float*  __restrict__ X,     // [B*L][DIN]
                 const __half* __restrict__ PW,    // [VV][DIN]
                 const __half* __restrict__ PEh,   // [VV][DOUT]
                 const int*    __restrict__ CIDX,  // [B*L][CC]
                 const int*    __restrict__ CMASK, // [B*L][CC]
                 const int*    __restrict__ SLEN,  // [B]
                 float*        __restrict__ OUT)   // [B*L][DOUT]
{
    const int t    = threadIdx.x;
    const int lane = t & 63;
    const int il   = lane & 15;    // lane within row-group
    const int rsub = lane >> 4;    // row within wave
    const int wid  = t >> 6;       // wave within block
    const int row  = blockIdx.x * 16 + wid * 4 + rsub;   // 0..65535

    const int  b     = row >> 12;
    const int  l     = row & (LL - 1);
    const bool inlen = l < SLEN[b];

    // ---- candidate indices + mask ----
    int  ci[CC];
    int  vmw[CC];
    #pragma unroll
    for (int c = 0; c < CC; ++c) ci[c]  = CIDX[(size_t)row * CC + c];
    #pragma unroll
    for (int c = 0; c < CC; ++c) vmw[c] = CMASK[(size_t)row * CC + c];

    // ---- X loads (independent; in flight while ci resolves) ----
    const float* xr = X + (size_t)row * DIN;
    float4 xf[8];
    #pragma unroll
    for (int j = 0; j < 4; ++j) {
        xf[j * 2 + 0] = *(const float4*)(xr + il * 8 + 128 * j);
        xf[j * 2 + 1] = *(const float4*)(xr + il * 8 + 128 * j + 4);
    }

    // ---- PW row pointers, issue batches 0 and 1 ----
    const __half* pwr[CC];
    #pragma unroll
    for (int c = 0; c < CC; ++c)
        pwr[c] = PW + (size_t)ci[c] * DIN + il * 8;

    uint4 bufA[CC], bufB[CC];
    pw_issue<0>(bufA, pwr);
    pw_issue<1>(bufB, pwr);

    // ---- convert x to half2 while PW batches are in flight ----
    h2 xh[16];
    #pragma unroll
    for (int q = 0; q < 8; ++q) {
        xh[q * 2 + 0] = pack_h2(xf[q].x, xf[q].y);
        xh[q * 2 + 1] = pack_h2(xf[q].z, xf[q].w);
    }

    float sc[CC];
    #pragma unroll
    for (int c = 0; c < CC; ++c) sc[c] = 0.f;

    // ---- pipelined consume/issue ----
    pw_consume<0>(bufA, xh, sc);
    pw_issue<2>(bufA, pwr);
    pw_consume<1>(bufB, xh, sc);
    pw_issue<3>(bufB, pwr);
    pw_consume<2>(bufA, xh, sc);

    // ---- PE gather issued early: hides under consume<3> + reduce + softmax ----
    uint4 peb[CC];
    #pragma unroll
    for (int c = 0; c < CC; ++c)
        peb[c] = *(const uint4*)(PEh + (size_t)ci[c] * DOUT + il * 8);

    pw_consume<3>(bufB, xh, sc);

    // ---- 16-lane reduce ----
    #pragma unroll
    for (int c = 0; c < CC; ++c) {
        float s = sc[c];
        s += __shfl_xor(s, 1);
        s += __shfl_xor(s, 2);
        s += __shfl_xor(s, 4);
        s += __shfl_xor(s, 8);
        sc[c] = s;
    }

    // ---- masked softmax (redundant per lane) ----
    bool any = false;
    float mx = -FLT_MAX;
    #pragma unroll
    for (int c = 0; c < CC; ++c) {
        if (vmw[c]) { mx = fmaxf(mx, sc[c]); any = true; }
    }
    float e[CC];
    float den = 0.f;
    #pragma unroll
    for (int c = 0; c < CC; ++c) {
        e[c] = vmw[c] ? __expf(sc[c] - mx) : 0.f;
        den += e[c];
    }
    const float scale = (any && inlen) ? (1.f / den) : 0.f;

    // ---- out dims [il*8 .. +8) = sum_c e[c] * PEh[ci[c]] ----
    float o[8];
    #pragma unroll
    for (int j = 0; j < 8; ++j) o[j] = 0.f;
    #pragma unroll
    for (int c = 0; c < CC; ++c) {
        const float w = e[c];
        h2 q0 = __builtin_bit_cast(h2, peb[c].x);
        h2 q1 = __builtin_bit_cast(h2, peb[c].y);
        h2 q2 = __builtin_bit_cast(h2, peb[c].z);
        h2 q3 = __builtin_bit_cast(h2, peb[c].w);
        o[0] = fmaf(w, (float)q0[0], o[0]); o[1] = fmaf(w, (float)q0[1], o[1]);
        o[2] = fmaf(w, (float)q1[0], o[2]); o[3] = fmaf(w, (float)q1[1], o[3]);
        o[4] = fmaf(w, (float)q2[0], o[4]); o[5] = fmaf(w, (float)q2[1], o[5]);
        o[6] = fmaf(w, (float)q3[0], o[6]); o[7] = fmaf(w, (float)q3[1], o[7]);
    }

    float* op = OUT + (size_t)row * DOUT + il * 8;
    *(float4*)op       = make_float4(o[0] * scale, o[1] * scale, o[2] * scale, o[3] * scale);
    *(float4*)(op + 4) = make_float4(o[4] * scale, o[5] * scale, o[6] * scale, o[7] * scale);
}

extern "C" void kernel_launch(void* const* d_in, const int* in_sizes, int n_in,
                              void* d_out, int out_size, void* d_ws, size_t ws_size,
                              hipStream_t stream) {
    const float* X  = (const float*)d_in[0];
    const float* W  = (const float*)d_in[1];
    const float* PE = (const float*)d_in[2];
    const int*   CI = (const int*)d_in[3];
    const int*   CM = (const int*)d_in[4];
    const int*   SL = (const int*)d_in[5];
    float* OUT = (float*)d_out;
    __half* PW  = (__half*)d_ws;                       // 96*512*2 = 96 KiB
    __half* PEh = (__half*)d_ws + (size_t)VV * DIN;    // +96*128*2 = 24 KiB

    hipLaunchKernelGGL(pw_kernel, dim3(VV, 4), dim3(128), 0, stream, W, PE, PW);
    hipLaunchKernelGGL(peh_kernel, dim3((VV * DOUT / 2) / 256), dim3(256), 0, stream, PE, PEh);

    const int rows = BB * LL;            // 65536
    hipLaunchKernelGGL(attn_kernel, dim3(rows / 16), dim3(256), 0, stream,
                       X, PW, PEh, CI, CM, SL, OUT);
}

// Round 8
// 45.245 us; speedup vs baseline: 5.6657x; 1.1533x over previous
//
#include <hip/hip_runtime.h>
#include <hip/hip_bf16.h>
#include <hip/hip_fp16.h>
#include <cfloat>

// Problem constants
#define BB   16
#define LL   4096
#define CC   9
#define DIN  512
#define DOUT 128
#define VV   96

// LDS layout (halves): padded row strides to rotate banks per vocab row
#define PWLD 520    // 512 + 8
#define PELD 136    // 128 + 8

typedef _Float16 h2 __attribute__((ext_vector_type(2)));

#if defined(__has_builtin)
#if __has_builtin(__builtin_amdgcn_fdot2)
#define FDOT2(a, b, c) __builtin_amdgcn_fdot2((a), (b), (c), false)
#endif
#endif
#ifndef FDOT2
__device__ __forceinline__ float FDOT2(h2 a, h2 b, float c) {
    return c + (float)a[0] * (float)b[0] + (float)a[1] * (float)b[1];
}
#endif

__device__ __forceinline__ h2 pack_h2(float lo, float hi) {
    return __builtin_bit_cast(h2, __builtin_amdgcn_cvt_pkrtz(lo, hi));
}

// ---------------------------------------------------------------------------
// Kernel 1: PW[v][k] = sum_o PE[v][o] * W[o][k]   (fp32 accumulate -> fp16)
// ---------------------------------------------------------------------------
__global__ __launch_bounds__(128)
void pw_kernel(const float* __restrict__ W,    // [DOUT][DIN]
               const float* __restrict__ PE,   // [VV][DOUT]
               __half*      __restrict__ PW)   // [VV][DIN]
{
    const int v = blockIdx.x;                       // 0..95
    const int k = blockIdx.y * 128 + threadIdx.x;   // 0..511
    const float* per = PE + v * DOUT;
    float a = 0.f;
    #pragma unroll 8
    for (int o = 0; o < DOUT; ++o)
        a = fmaf(per[o], W[(size_t)o * DIN + k], a);
    PW[(size_t)v * DIN + k] = __float2half_rn(a);
}

// ---------------------------------------------------------------------------
// Kernel 1b: PEh = fp16(PE)
// ---------------------------------------------------------------------------
__global__ __launch_bounds__(256)
void peh_kernel(const float* __restrict__ PE, __half* __restrict__ PEh)
{
    const int i = blockIdx.x * 256 + threadIdx.x;   // half2 units
    float2 f = ((const float2*)PE)[i];
    ((__half2*)PEh)[i] = __floats2half2_rn(f.x, f.y);
}

// ---------------------------------------------------------------------------
// Kernel 2: PW + PEh staged in LDS; 16 lanes/row; 1024 thr = 64 row-slots;
// 128 rows per block over 2 iterations.
// ---------------------------------------------------------------------------
__global__ __launch_bounds__(1024, 1)
void attn_kernel(const float*  __restrict__ X,     // [B*L][DIN]
                 const __half* __restrict__ PW,    // [VV][DIN]
                 const __half* __restrict__ PEh,   // [VV][DOUT]
                 const int*    __restrict__ CIDX,  // [B*L][CC]
                 const int*    __restrict__ CMASK, // [B*L][CC]
                 const int*    __restrict__ SLEN,  // [B]
                 float*        __restrict__ OUT)   // [B*L][DOUT]
{
    __shared__ __half lds_pw[VV * PWLD];   // 99840 B
    __shared__ __half lds_pe[VV * PELD];   // 26112 B

    const int t = threadIdx.x;

    // ---- stage PW: 96*512/8 = 6144 uint4 chunks, 6 per thread ----
    #pragma unroll
    for (int it = 0; it < 6; ++it) {
        int chunk = t + it * 1024;
        int v = chunk >> 6, kq = chunk & 63;
        uint4 d = *(const uint4*)(PW + (size_t)v * DIN + kq * 8);
        *(uint4*)&lds_pw[v * PWLD + kq * 8] = d;
    }
    // ---- stage PEh: 96*128/8 = 1536 chunks ----
    {
        int v = t >> 4, kq = t & 15;
        if (t < 1536)
            *(uint4*)&lds_pe[v * PELD + kq * 8] =
                *(const uint4*)(PEh + (size_t)v * DOUT + kq * 8);
        int c2 = t + 1024;
        if (c2 < 1536) {
            int v2 = c2 >> 4, k2 = c2 & 15;
            *(uint4*)&lds_pe[v2 * PELD + k2 * 8] =
                *(const uint4*)(PEh + (size_t)v2 * DOUT + k2 * 8);
        }
    }
    __syncthreads();

    const int lane = t & 63;
    const int il   = lane & 15;          // lane within row-group
    const int slot = t >> 4;             // 0..63 row-slot in block
    const int rowbase = blockIdx.x * 128;

    #pragma unroll
    for (int iter = 0; iter < 2; ++iter) {
        const int row = rowbase + iter * 64 + slot;
        const int  b     = row >> 12;
        const int  l     = row & (LL - 1);
        const bool inlen = l < SLEN[b];

        // ---- candidate indices + mask ----
        int ci[CC], vmw[CC];
        #pragma unroll
        for (int c = 0; c < CC; ++c) ci[c]  = CIDX[(size_t)row * CC + c];
        #pragma unroll
        for (int c = 0; c < CC; ++c) vmw[c] = CMASK[(size_t)row * CC + c];

        // ---- X loads ----
        const float* xr = X + (size_t)row * DIN;
        float4 xf[8];
        #pragma unroll
        for (int j = 0; j < 4; ++j) {
            xf[j * 2 + 0] = *(const float4*)(xr + il * 8 + 128 * j);
            xf[j * 2 + 1] = *(const float4*)(xr + il * 8 + 128 * j + 4);
        }
        h2 xh[16];
        #pragma unroll
        for (int q = 0; q < 8; ++q) {
            xh[q * 2 + 0] = pack_h2(xf[q].x, xf[q].y);
            xh[q * 2 + 1] = pack_h2(xf[q].z, xf[q].w);
        }

        // ---- scores from LDS PW ----
        float sc[CC];
        #pragma unroll
        for (int c = 0; c < CC; ++c) sc[c] = 0.f;
        #pragma unroll
        for (int j = 0; j < 4; ++j) {
            #pragma unroll
            for (int c = 0; c < CC; ++c) {
                uint4 pwb = *(const uint4*)&lds_pw[ci[c] * PWLD + j * 128 + il * 8];
                h2 p0 = __builtin_bit_cast(h2, pwb.x);
                h2 p1 = __builtin_bit_cast(h2, pwb.y);
                h2 p2 = __builtin_bit_cast(h2, pwb.z);
                h2 p3 = __builtin_bit_cast(h2, pwb.w);
                float s = sc[c];
                s = FDOT2(xh[j * 4 + 0], p0, s);
                s = FDOT2(xh[j * 4 + 1], p1, s);
                s = FDOT2(xh[j * 4 + 2], p2, s);
                s = FDOT2(xh[j * 4 + 3], p3, s);
                sc[c] = s;
            }
        }
        #pragma unroll
        for (int c = 0; c < CC; ++c) {
            float s = sc[c];
            s += __shfl_xor(s, 1);
            s += __shfl_xor(s, 2);
            s += __shfl_xor(s, 4);
            s += __shfl_xor(s, 8);
            sc[c] = s;
        }

        // ---- masked softmax (redundant per lane) ----
        bool any = false;
        float mx = -FLT_MAX;
        #pragma unroll
        for (int c = 0; c < CC; ++c)
            if (vmw[c]) { mx = fmaxf(mx, sc[c]); any = true; }
        float e[CC];
        float den = 0.f;
        #pragma unroll
        for (int c = 0; c < CC; ++c) {
            e[c] = vmw[c] ? __expf(sc[c] - mx) : 0.f;
            den += e[c];
        }
        const float scale = (any && inlen) ? (1.f / den) : 0.f;

        // ---- weighted PE sum from LDS ----
        float o[8];
        #pragma unroll
        for (int j = 0; j < 8; ++j) o[j] = 0.f;
        #pragma unroll
        for (int c = 0; c < CC; ++c) {
            const float w = e[c];
            uint4 peb = *(const uint4*)&lds_pe[ci[c] * PELD + il * 8];
            h2 q0 = __builtin_bit_cast(h2, peb.x);
            h2 q1 = __builtin_bit_cast(h2, peb.y);
            h2 q2 = __builtin_bit_cast(h2, peb.z);
            h2 q3 = __builtin_bit_cast(h2, peb.w);
            o[0] = fmaf(w, (float)q0[0], o[0]); o[1] = fmaf(w, (float)q0[1], o[1]);
            o[2] = fmaf(w, (float)q1[0], o[2]); o[3] = fmaf(w, (float)q1[1], o[3]);
            o[4] = fmaf(w, (float)q2[0], o[4]); o[5] = fmaf(w, (float)q2[1], o[5]);
            o[6] = fmaf(w, (float)q3[0], o[6]); o[7] = fmaf(w, (float)q3[1], o[7]);
        }

        float* op = OUT + (size_t)row * DOUT + il * 8;
        *(float4*)op       = make_float4(o[0] * scale, o[1] * scale, o[2] * scale, o[3] * scale);
        *(float4*)(op + 4) = make_float4(o[4] * scale, o[5] * scale, o[6] * scale, o[7] * scale);
    }
}

extern "C" void kernel_launch(void* const* d_in, const int* in_sizes, int n_in,
                              void* d_out, int out_size, void* d_ws, size_t ws_size,
                              hipStream_t stream) {
    const float* X  = (const float*)d_in[0];
    const float* W  = (const float*)d_in[1];
    const float* PE = (const float*)d_in[2];
    const int*   CI = (const int*)d_in[3];
    const int*   CM = (const int*)d_in[4];
    const int*   SL = (const int*)d_in[5];
    float* OUT = (float*)d_out;
    __half* PW  = (__half*)d_ws;                       // 96*512*2 = 96 KiB
    __half* PEh = (__half*)d_ws + (size_t)VV * DIN;    // +96*128*2 = 24 KiB

    hipLaunchKernelGGL(pw_kernel, dim3(VV, 4), dim3(128), 0, stream, W, PE, PW);
    hipLaunchKernelGGL(peh_kernel, dim3((VV * DOUT / 2) / 256), dim3(256), 0, stream, PE, PEh);

    const int rows = BB * LL;            // 65536
    hipLaunchKernelGGL(attn_kernel, dim3(rows / 128), dim3(1024), 0, stream,
                       X, PW, PEh, CI, CM, SL, OUT);
}